// Round 5
// baseline (946.948 us; speedup 1.0000x reference)
//
#include <hip/hip_runtime.h>
#include <hip/hip_bf16.h>
#include <math.h>

typedef unsigned short u16;
typedef __bf16 bf16x8 __attribute__((ext_vector_type(8)));
typedef short s16x4 __attribute__((ext_vector_type(4)));
typedef float f32x4 __attribute__((ext_vector_type(4)));

#define B_   8
#define NQ   1024
#define NC   2048
#define IND  768
#define DIM  384
#define NH   6
#define HD   64
#define HID  3072

__device__ __forceinline__ u16 f2b(float f){
  unsigned int x = __float_as_uint(f);
  return (u16)((x + 0x7fffu + ((x >> 16) & 1u)) >> 16);
}

__device__ __forceinline__ void gl_lds16(const u16* g, u16* l){
  __builtin_amdgcn_global_load_lds(
    (const __attribute__((address_space(1))) unsigned int*)g,
    (__attribute__((address_space(3))) unsigned int*)l, 16, 0, 0);
}

// ---- weight convert+transpose: W (K x N) fp32 -> Wt (N x K) bf16 ----
__global__ void wtrans_kernel(const float* __restrict__ W, u16* __restrict__ Wt,
                              int K, int N){
  __shared__ float tile[32][33];
  int n0 = blockIdx.x * 32, k0 = blockIdx.y * 32;
  int tx = threadIdx.x, ty = threadIdx.y;   // 32 x 8
  #pragma unroll
  for(int i=0;i<4;i++) tile[ty*4+i][tx] = W[(size_t)(k0+ty*4+i)*N + n0 + tx];
  __syncthreads();
  #pragma unroll
  for(int i=0;i<4;i++) Wt[(size_t)(n0+ty*4+i)*K + k0 + tx] = f2b(tile[tx][ty*4+i]);
}

// ---- V transpose: KV (b, m, 2, h, d) -> Vt (b, h, d, m) bf16 ----
__global__ void vtrans_kernel(const u16* __restrict__ KV, u16* __restrict__ Vt, int M){
  __shared__ u16 t[64][72];
  int bh = blockIdx.y; int b = bh / NH, h = bh % NH;
  int m0 = blockIdx.x * 64;
  int tx = threadIdx.x & 63, ty = threadIdx.x >> 6;   // 64 x 4
  #pragma unroll
  for(int i=0;i<16;i++){
    int mm = ty*16+i;
    t[mm][tx] = KV[(size_t)(b*M + m0 + mm)*(2*DIM) + DIM + h*HD + tx];
  }
  __syncthreads();
  #pragma unroll
  for(int i=0;i<16;i++){
    int dd = ty*16+i;
    Vt[(size_t)(bh*HD + dd)*M + m0 + tx] = t[tx][dd];
  }
}

// ---- layernorm over rows of 768: fp32 in -> bf16 out (+optional fp32 out) ----
template<bool ALSO_F32>
__global__ void ln_kernel(const float* __restrict__ x, const float* __restrict__ w,
                          const float* __restrict__ bia, u16* __restrict__ yb,
                          float* __restrict__ yf){
  int row = blockIdx.x;
  const float* xr = x + (size_t)row * IND;
  int t = threadIdx.x;
  float v[3];
  v[0] = xr[t]; v[1] = xr[t+256]; v[2] = xr[t+512];
  float s  = v[0]+v[1]+v[2];
  float sq = v[0]*v[0]+v[1]*v[1]+v[2]*v[2];
  #pragma unroll
  for(int o=1;o<64;o<<=1){ s += __shfl_xor(s, o, 64); sq += __shfl_xor(sq, o, 64); }
  __shared__ float ss[4], ssq[4];
  int wid = t >> 6;
  if((t&63)==0){ ss[wid]=s; ssq[wid]=sq; }
  __syncthreads();
  s  = ss[0]+ss[1]+ss[2]+ss[3];
  sq = ssq[0]+ssq[1]+ssq[2]+ssq[3];
  float mean = s * (1.0f/IND);
  float var  = sq * (1.0f/IND) - mean*mean;
  float rs   = rsqrtf(var + 1e-5f);
  #pragma unroll
  for(int i=0;i<3;i++){
    int idx = t + i*256;
    float y = (v[i]-mean)*rs*w[idx] + bia[idx];
    yb[(size_t)row*IND + idx] = f2b(y);
    if(ALSO_F32) yf[(size_t)row*IND + idx] = y;
  }
}

// ---- NT GEMM: C(rows x N) = A(rows x Kstr) @ Wt(N x Kstr)^T, 16x16x32 MFMA ----
// Split-K over blockIdx.z, each block covers Kc columns starting z*Kc.
// OUTM: 0 = bf16 store, 1 = fp32 store, 2 = fp32 += (single writer),
//       3 = fp32 atomicAdd (split-K; bias added by z==0 only)
template<int OUTM, bool BIAS, bool GELU_>
__global__ __launch_bounds__(256) void gemm_bt(const u16* __restrict__ A,
    const u16* __restrict__ Wt, const float* __restrict__ bias,
    void* __restrict__ C, int Kstr, int Kc, int N){
  __shared__ __align__(16) u16 As[128][32];   // rows are 64B: lane i -> base + i*16
  __shared__ __align__(16) u16 Bs[128][32];
  int rowblk = blockIdx.x * 128, colblk = blockIdx.y * 128;
  int kbase = blockIdx.z * Kc;
  int tid = threadIdx.x;
  int lane = tid & 63, wv = tid >> 6;
  int wm = (wv >> 1) * 64, wn = (wv & 1) * 64;
  int l16 = lane & 15, quad = lane >> 4;
  f32x4 acc[4][4] = {};
  int sr = lane >> 2, sc = (lane & 3) * 8;
  const u16* Ap = A  + (size_t)(rowblk + wv*16 + sr) * Kstr + kbase + sc;
  const u16* Bp = Wt + (size_t)(colblk + wv*16 + sr) * Kstr + kbase + sc;
  u16* lA0 = &As[wv*16][0];      u16* lA1 = &As[64 + wv*16][0];
  u16* lB0 = &Bs[wv*16][0];      u16* lB1 = &Bs[64 + wv*16][0];
  for(int kt = 0; kt < Kc; kt += 32){
    gl_lds16(Ap + kt,                    lA0);
    gl_lds16(Ap + (size_t)64*Kstr + kt,  lA1);
    gl_lds16(Bp + kt,                    lB0);
    gl_lds16(Bp + (size_t)64*Kstr + kt,  lB1);
    __syncthreads();
    bf16x8 af[4], bfr[4];
    #pragma unroll
    for(int i=0;i<4;i++) af[i]  = *(const bf16x8*)&As[wm + i*16 + l16][quad*8];
    #pragma unroll
    for(int j=0;j<4;j++) bfr[j] = *(const bf16x8*)&Bs[wn + j*16 + l16][quad*8];
    #pragma unroll
    for(int i=0;i<4;i++)
      #pragma unroll
      for(int j=0;j<4;j++)
        acc[i][j] = __builtin_amdgcn_mfma_f32_16x16x32_bf16(af[i], bfr[j], acc[i][j], 0, 0, 0);
    __syncthreads();
  }
  bool addb = BIAS && (OUTM != 3 || blockIdx.z == 0);
  #pragma unroll
  for(int i=0;i<4;i++){
    #pragma unroll
    for(int j=0;j<4;j++){
      int grow = rowblk + wm + i*16 + quad*4;
      int gcol = colblk + wn + j*16 + l16;
      float bv = addb ? bias[gcol] : 0.0f;
      #pragma unroll
      for(int rg=0; rg<4; rg++){
        float vval = acc[i][j][rg] + bv;
        if(GELU_) vval = 0.5f * vval * (1.0f + erff(vval * 0.70710678118f));
        size_t idx = (size_t)(grow + rg) * N + gcol;
        if(OUTM == 0)      ((u16*)C)[idx]   = f2b(vval);
        else if(OUTM == 1) ((float*)C)[idx] = vval;
        else if(OUTM == 2) ((float*)C)[idx] += vval;
        else               atomicAdd(&((float*)C)[idx], vval);
      }
    }
  }
}

// ---- flash attention: S^T=K.Q^T register chaining + coalesced LDS staging ----
__global__ __launch_bounds__(256) void attn_kernel(const u16* __restrict__ Q,
    const u16* __restrict__ KV, const u16* __restrict__ Vtg,
    u16* __restrict__ AO, int M){
  __shared__ __align__(16) u16 Ks[128][68];   // [ctx][d]  +4 pad
  __shared__ __align__(16) u16 Vs[64][132];   // [d][ctx]  +4 pad
  int tid = threadIdx.x, lane = tid & 63, wv = tid >> 6;
  int qt = blockIdx.x & (NQ/64 - 1);
  int bh = blockIdx.x >> 4;
  int h = bh % NH, b = bh / NH;
  int l16 = lane & 15, quad = lane >> 4;
  const float sc2 = 0.18033688011f;   // d^-0.5 * log2(e)

  s16x4 qf[4];
  const u16* qp = Q + (size_t)(b*NQ + qt*64 + wv*16 + l16) * DIM + h*HD + quad*4;
  #pragma unroll
  for(int s=0;s<4;s++) qf[s] = *(const s16x4*)(qp + s*16);

  f32x4 o[4] = {};
  float lacc = 0.f;

  for(int cb = 0; cb < M; cb += 128){
    __syncthreads();
    #pragma unroll
    for(int it=0; it<4; it++){
      int idx = tid + it*256;
      int row = idx >> 3, c8 = (idx & 7) * 8;
      *(int4*)&Ks[row][c8] =
        *(const int4*)(KV + (size_t)(b*M + cb + row)*(2*DIM) + h*HD + c8);
    }
    #pragma unroll
    for(int it=0; it<4; it++){
      int idx = tid + it*256;
      int dd = idx >> 4, c8 = (idx & 15) * 8;
      *(int4*)&Vs[dd][c8] =
        *(const int4*)(Vtg + (size_t)(bh*HD + dd)*M + cb + c8);
    }
    __syncthreads();

    s16x4 pp[8];
    #pragma unroll
    for(int cc=0; cc<8; cc++){
      f32x4 z = {};
      #pragma unroll
      for(int s=0;s<4;s++){
        s16x4 kf = *(const s16x4*)&Ks[cc*16 + l16][quad*4 + s*16];
        z = __builtin_amdgcn_mfma_f32_16x16x16bf16_1k(kf, qf[s], z, 0,0,0);
      }
      f32x4 p;
      #pragma unroll
      for(int j=0;j<4;j++) p[j] = exp2f(z[j]*sc2);
      lacc += (p[0]+p[1]) + (p[2]+p[3]);
      s16x4 pb;
      #pragma unroll
      for(int j=0;j<4;j++) pb[j] = (short)f2b(p[j]);
      pp[cc] = pb;
    }
    #pragma unroll
    for(int dn=0;dn<4;dn++){
      #pragma unroll
      for(int t=0;t<8;t++){
        s16x4 vf = *(const s16x4*)&Vs[dn*16 + l16][quad*4 + t*16];
        o[dn] = __builtin_amdgcn_mfma_f32_16x16x16bf16_1k(vf, pp[t], o[dn], 0,0,0);
      }
    }
  }

  lacc += __shfl_xor(lacc, 16, 64);
  lacc += __shfl_xor(lacc, 32, 64);
  float rl = 1.0f / lacc;

  u16* aop = AO + (size_t)(b*NQ + qt*64 + wv*16 + l16) * DIM + h*HD + quad*4;
  #pragma unroll
  for(int dn=0;dn<4;dn++){
    s16x4 ob;
    #pragma unroll
    for(int r=0;r<4;r++) ob[r] = (short)f2b(o[dn][r] * rl);
    *(s16x4*)(aop + dn*16) = ob;
  }
}

extern "C" void kernel_launch(void* const* d_in, const int* in_sizes, int n_in,
                              void* d_out, int out_size, void* d_ws, size_t ws_size,
                              hipStream_t stream){
  const float* query   = (const float*)d_in[0];
  const float* context = (const float*)d_in[1];
  const float* ln_w  = (const float*)d_in[2];
  const float* ln_b  = (const float*)d_in[3];
  const float* a1_wq = (const float*)d_in[4];
  const float* a1_wkv= (const float*)d_in[5];
  const float* a1_wp = (const float*)d_in[6];
  const float* a1_bp = (const float*)d_in[7];
  const float* m1_w1 = (const float*)d_in[8];
  const float* m1_b1 = (const float*)d_in[9];
  const float* m1_w2 = (const float*)d_in[10];
  const float* m1_b2 = (const float*)d_in[11];
  const float* a2_wq = (const float*)d_in[12];
  const float* a2_wkv= (const float*)d_in[13];
  const float* a2_wp = (const float*)d_in[14];
  const float* a2_bp = (const float*)d_in[15];
  const float* m2_w1 = (const float*)d_in[16];
  const float* m2_b1 = (const float*)d_in[17];
  const float* m2_w2 = (const float*)d_in[18];
  const float* m2_b2 = (const float*)d_in[19];
  (void)in_sizes; (void)n_in; (void)out_size; (void)ws_size;

  float* c_out = (float*)d_out;                    // output 0: c (8,1024,768) fp32
  float* q_out = c_out + (size_t)B_*NQ*IND;        // output 1: q (8,1024,768) fp32

  char* base = (char*)d_ws;
  size_t off = 0;
  auto alloc = [&](size_t elems)->u16*{
    u16* p = (u16*)(base + off);
    off += ((elems*2) + 255) & ~(size_t)255;
    return p;
  };
  u16* wq1t  = alloc((size_t)DIM*IND);
  u16* wkv1t = alloc((size_t)2*DIM*IND);
  u16* wp1t  = alloc((size_t)IND*DIM);
  u16* w11t  = alloc((size_t)HID*IND);
  u16* w21t  = alloc((size_t)IND*HID);
  u16* wq2t  = alloc((size_t)DIM*IND);
  u16* wkv2t = alloc((size_t)2*DIM*IND);
  u16* wp2t  = alloc((size_t)IND*DIM);
  u16* w12t  = alloc((size_t)HID*IND);
  u16* w22t  = alloc((size_t)IND*HID);
  u16* qn_b  = alloc((size_t)B_*NQ*IND);
  u16* cn_b  = alloc((size_t)B_*NC*IND);
  u16* Tb    = alloc((size_t)B_*NQ*IND);
  u16* Qb    = alloc((size_t)B_*NQ*DIM);
  u16* KVb   = alloc((size_t)B_*NC*2*DIM);
  u16* AOb   = alloc((size_t)B_*NQ*DIM);
  u16* Hb    = alloc((size_t)B_*NQ*HID);
  u16* Vtb   = Hb;   // alias: Hb idle during attention phases

  dim3 tb(32,8);
  wtrans_kernel<<<dim3(DIM/32,   IND/32), tb, 0, stream>>>(a1_wq,  wq1t,  IND, DIM);
  wtrans_kernel<<<dim3(2*DIM/32, IND/32), tb, 0, stream>>>(a1_wkv, wkv1t, IND, 2*DIM);
  wtrans_kernel<<<dim3(IND/32,   DIM/32), tb, 0, stream>>>(a1_wp,  wp1t,  DIM, IND);
  wtrans_kernel<<<dim3(HID/32,   IND/32), tb, 0, stream>>>(m1_w1,  w11t,  IND, HID);
  wtrans_kernel<<<dim3(IND/32,   HID/32), tb, 0, stream>>>(m1_w2,  w21t,  HID, IND);
  wtrans_kernel<<<dim3(DIM/32,   IND/32), tb, 0, stream>>>(a2_wq,  wq2t,  IND, DIM);
  wtrans_kernel<<<dim3(2*DIM/32, IND/32), tb, 0, stream>>>(a2_wkv, wkv2t, IND, 2*DIM);
  wtrans_kernel<<<dim3(IND/32,   DIM/32), tb, 0, stream>>>(a2_wp,  wp2t,  DIM, IND);
  wtrans_kernel<<<dim3(HID/32,   IND/32), tb, 0, stream>>>(m2_w1,  w12t,  IND, HID);
  wtrans_kernel<<<dim3(IND/32,   HID/32), tb, 0, stream>>>(m2_w2,  w22t,  HID, IND);

  ln_kernel<true ><<<B_*NQ, 256, 0, stream>>>(query,   ln_w, ln_b, qn_b, q_out);
  ln_kernel<false><<<B_*NC, 256, 0, stream>>>(context, ln_w, ln_b, cn_b, nullptr);

  // --- block 1: cross-attention ---
  gemm_bt<0,false,false><<<dim3(B_*NQ/128, DIM/128),   256, 0, stream>>>(qn_b, wq1t,  nullptr, Qb,  IND, IND, DIM);
  gemm_bt<0,false,false><<<dim3(B_*NC/128, 2*DIM/128), 256, 0, stream>>>(cn_b, wkv1t, nullptr, KVb, IND, IND, 2*DIM);
  vtrans_kernel<<<dim3(NC/64, B_*NH), 256, 0, stream>>>(KVb, Vtb, NC);
  attn_kernel<<<B_*NH*(NQ/64), 256, 0, stream>>>(Qb, KVb, Vtb, AOb, NC);
  // proj1: fresh fp32 output -> zero first, then split-K atomic accumulate
  hipMemsetAsync(c_out, 0, (size_t)B_*NQ*IND*sizeof(float), stream);
  gemm_bt<3,true,false><<<dim3(B_*NQ/128, IND/128, 2), 256, 0, stream>>>(AOb, wp1t, a1_bp, c_out, DIM, DIM/2, IND);
  // --- MLP 1 ---
  ln_kernel<false><<<B_*NQ, 256, 0, stream>>>(c_out, ln_w, ln_b, Tb, nullptr);
  gemm_bt<0,true,true ><<<dim3(B_*NQ/128, HID/128), 256, 0, stream>>>(Tb, w11t, m1_b1, Hb, IND, IND, HID);
  gemm_bt<3,true,false><<<dim3(B_*NQ/128, IND/128, 4), 256, 0, stream>>>(Hb, w21t, m1_b2, c_out, HID, HID/4, IND);
  // --- block 2: cross-attention (q reused, kv from LN(c)) ---
  ln_kernel<false><<<B_*NQ, 256, 0, stream>>>(c_out, ln_w, ln_b, Tb, nullptr);
  gemm_bt<0,false,false><<<dim3(B_*NQ/128, DIM/128),   256, 0, stream>>>(qn_b, wq2t,  nullptr, Qb,  IND, IND, DIM);
  gemm_bt<0,false,false><<<dim3(B_*NQ/128, 2*DIM/128), 256, 0, stream>>>(Tb,   wkv2t, nullptr, KVb, IND, IND, 2*DIM);
  vtrans_kernel<<<dim3(NQ/64, B_*NH), 256, 0, stream>>>(KVb, Vtb, NQ);
  attn_kernel<<<B_*NH*(NQ/64), 256, 0, stream>>>(Qb, KVb, Vtb, AOb, NQ);
  gemm_bt<3,true,false><<<dim3(B_*NQ/128, IND/128, 2), 256, 0, stream>>>(AOb, wp2t, a2_bp, c_out, DIM, DIM/2, IND);
  // --- MLP 2 ---
  ln_kernel<false><<<B_*NQ, 256, 0, stream>>>(c_out, ln_w, ln_b, Tb, nullptr);
  gemm_bt<0,true,true ><<<dim3(B_*NQ/128, HID/128), 256, 0, stream>>>(Tb, w12t, m2_b1, Hb, IND, IND, HID);
  gemm_bt<3,true,false><<<dim3(B_*NQ/128, IND/128, 4), 256, 0, stream>>>(Hb, w22t, m2_b2, c_out, HID, HID/4, IND);
}

// Round 6
// 767.068 us; speedup vs baseline: 1.2345x; 1.2345x over previous
//
#include <hip/hip_runtime.h>
#include <hip/hip_bf16.h>
#include <math.h>

typedef unsigned short u16;
typedef __bf16 bf16x8 __attribute__((ext_vector_type(8)));
typedef short s16x4 __attribute__((ext_vector_type(4)));
typedef float f32x4 __attribute__((ext_vector_type(4)));

#define B_   8
#define NQ   1024
#define NC   2048
#define IND  768
#define DIM  384
#define NH   6
#define HD   64
#define HID  3072

__device__ __forceinline__ u16 f2b(float f){
  unsigned int x = __float_as_uint(f);
  return (u16)((x + 0x7fffu + ((x >> 16) & 1u)) >> 16);
}

__device__ __forceinline__ void gl_lds16(const u16* g, u16* l){
  __builtin_amdgcn_global_load_lds(
    (const __attribute__((address_space(1))) unsigned int*)g,
    (__attribute__((address_space(3))) unsigned int*)l, 16, 0, 0);
}

// ---- weight convert+transpose: W (K x N) fp32 -> Wt (N x K) bf16 ----
__global__ void wtrans_kernel(const float* __restrict__ W, u16* __restrict__ Wt,
                              int K, int N){
  __shared__ float tile[32][33];
  int n0 = blockIdx.x * 32, k0 = blockIdx.y * 32;
  int tx = threadIdx.x, ty = threadIdx.y;   // 32 x 8
  #pragma unroll
  for(int i=0;i<4;i++) tile[ty*4+i][tx] = W[(size_t)(k0+ty*4+i)*N + n0 + tx];
  __syncthreads();
  #pragma unroll
  for(int i=0;i<4;i++) Wt[(size_t)(n0+ty*4+i)*K + k0 + tx] = f2b(tile[tx][ty*4+i]);
}

// ---- V transpose: KV (b, m, 2, h, d) -> Vt (b, h, d, m) bf16 ----
__global__ void vtrans_kernel(const u16* __restrict__ KV, u16* __restrict__ Vt, int M){
  __shared__ u16 t[64][72];
  int bh = blockIdx.y; int b = bh / NH, h = bh % NH;
  int m0 = blockIdx.x * 64;
  int tx = threadIdx.x & 63, ty = threadIdx.x >> 6;   // 64 x 4
  #pragma unroll
  for(int i=0;i<16;i++){
    int mm = ty*16+i;
    t[mm][tx] = KV[(size_t)(b*M + m0 + mm)*(2*DIM) + DIM + h*HD + tx];
  }
  __syncthreads();
  #pragma unroll
  for(int i=0;i<16;i++){
    int dd = ty*16+i;
    Vt[(size_t)(bh*HD + dd)*M + m0 + tx] = t[tx][dd];
  }
}

// ---- layernorm over rows of 768: fp32 in -> bf16 out (+optional fp32 out) ----
template<bool ALSO_F32>
__global__ void ln_kernel(const float* __restrict__ x, const float* __restrict__ w,
                          const float* __restrict__ bia, u16* __restrict__ yb,
                          float* __restrict__ yf){
  int row = blockIdx.x;
  const float* xr = x + (size_t)row * IND;
  int t = threadIdx.x;
  float v[3];
  v[0] = xr[t]; v[1] = xr[t+256]; v[2] = xr[t+512];
  float s  = v[0]+v[1]+v[2];
  float sq = v[0]*v[0]+v[1]*v[1]+v[2]*v[2];
  #pragma unroll
  for(int o=1;o<64;o<<=1){ s += __shfl_xor(s, o, 64); sq += __shfl_xor(sq, o, 64); }
  __shared__ float ss[4], ssq[4];
  int wid = t >> 6;
  if((t&63)==0){ ss[wid]=s; ssq[wid]=sq; }
  __syncthreads();
  s  = ss[0]+ss[1]+ss[2]+ss[3];
  sq = ssq[0]+ssq[1]+ssq[2]+ssq[3];
  float mean = s * (1.0f/IND);
  float var  = sq * (1.0f/IND) - mean*mean;
  float rs   = rsqrtf(var + 1e-5f);
  #pragma unroll
  for(int i=0;i<3;i++){
    int idx = t + i*256;
    float y = (v[i]-mean)*rs*w[idx] + bia[idx];
    yb[(size_t)row*IND + idx] = f2b(y);
    if(ALSO_F32) yf[(size_t)row*IND + idx] = y;
  }
}

// ---- NT GEMM: C(rows x N) = A(rows x K) @ Wt(N x K)^T, bf16 MFMA 16x16x32 ----
// Tile 128 x TN (TN = 128 or 64). XOR chunk swizzle kills the 8-way LDS
// read conflict while keeping the gl_lds lane*16 contiguity constraint.
// OUTM: 0 = bf16 store, 1 = fp32 store, 2 = fp32 += (single writer)
template<int TN, int OUTM, bool BIAS, bool GELU_>
__global__ __launch_bounds__(256) void gemm_bt(const u16* __restrict__ A,
    const u16* __restrict__ Wt, const float* __restrict__ bias,
    void* __restrict__ C, int K, int N){
  constexpr int JT = TN / 32;                 // b-tiles per wave (4 or 2)
  __shared__ __align__(16) u16 As[128][32];
  __shared__ __align__(16) u16 Bs[TN][32];
  int rowblk = blockIdx.x * 128, colblk = blockIdx.y * TN;
  int tid = threadIdx.x;
  int lane = tid & 63, wv = tid >> 6;
  int wm = (wv >> 1) * 64, wn = (wv & 1) * (16*JT);
  int l16 = lane & 15, quad = lane >> 4;
  f32x4 acc[4][JT] = {};
  int sr = lane >> 2;
  int sc = (((lane & 3) ^ ((lane >> 3) & 3)) * 8);   // staged chunk (XOR swizzle)
  int rc = ((quad ^ ((l16 >> 1) & 3)) * 8);          // read-back column
  const u16* Ap = A  + (size_t)(rowblk + wv*16 + sr) * K + sc;
  const u16* Bp = Wt + (size_t)(colblk + wv*16 + sr) * K + sc;
  u16* lA0 = &As[wv*16][0];      u16* lA1 = &As[64 + wv*16][0];
  u16* lB0 = &Bs[wv*16][0];
  for(int kt = 0; kt < K; kt += 32){
    gl_lds16(Ap + kt,                 lA0);
    gl_lds16(Ap + (size_t)64*K + kt,  lA1);
    gl_lds16(Bp + kt,                 lB0);
    if(TN == 128){
      gl_lds16(Bp + (size_t)64*K + kt, &Bs[0][0] + (64 + wv*16)*32);
    }
    __syncthreads();
    bf16x8 af[4], bfr[JT];
    #pragma unroll
    for(int i=0;i<4;i++)  af[i]  = *(const bf16x8*)&As[wm + i*16 + l16][rc];
    #pragma unroll
    for(int j=0;j<JT;j++) bfr[j] = *(const bf16x8*)&Bs[wn + j*16 + l16][rc];
    #pragma unroll
    for(int i=0;i<4;i++)
      #pragma unroll
      for(int j=0;j<JT;j++)
        acc[i][j] = __builtin_amdgcn_mfma_f32_16x16x32_bf16(af[i], bfr[j], acc[i][j], 0, 0, 0);
    __syncthreads();
  }
  #pragma unroll
  for(int i=0;i<4;i++){
    #pragma unroll
    for(int j=0;j<JT;j++){
      int grow = rowblk + wm + i*16 + quad*4;
      int gcol = colblk + wn + j*16 + l16;
      float bv = BIAS ? bias[gcol] : 0.0f;
      #pragma unroll
      for(int rg=0; rg<4; rg++){
        float vval = acc[i][j][rg] + bv;
        if(GELU_) vval = 0.5f * vval * (1.0f + erff(vval * 0.70710678118f));
        size_t idx = (size_t)(grow + rg) * N + gcol;
        if(OUTM == 0)      ((u16*)C)[idx]   = f2b(vval);
        else if(OUTM == 1) ((float*)C)[idx] = vval;
        else               ((float*)C)[idx] += vval;
      }
    }
  }
}

// ---- flash attention: S^T=K.Q^T register chaining + coalesced LDS staging ----
// Block decode puts all q-tiles of one (b,h) on the same XCD (48 % 8 == 0).
__global__ __launch_bounds__(256) void attn_kernel(const u16* __restrict__ Q,
    const u16* __restrict__ KV, const u16* __restrict__ Vtg,
    u16* __restrict__ AO, int M){
  __shared__ __align__(16) u16 Ks[128][68];   // [ctx][d]  +4 pad
  __shared__ __align__(16) u16 Vs[64][132];   // [d][ctx]  +4 pad
  int tid = threadIdx.x, lane = tid & 63, wv = tid >> 6;
  int bh = blockIdx.x % (B_*NH);              // XCD = bh % 8 for all its q-tiles
  int qt = blockIdx.x / (B_*NH);
  int h = bh % NH, b = bh / NH;
  int l16 = lane & 15, quad = lane >> 4;
  const float sc2 = 0.18033688011f;   // d^-0.5 * log2(e)

  s16x4 qf[4];
  const u16* qp = Q + (size_t)(b*NQ + qt*64 + wv*16 + l16) * DIM + h*HD + quad*4;
  #pragma unroll
  for(int s=0;s<4;s++) qf[s] = *(const s16x4*)(qp + s*16);

  f32x4 o[4] = {};
  float lacc = 0.f;

  for(int cb = 0; cb < M; cb += 128){
    __syncthreads();
    #pragma unroll
    for(int it=0; it<4; it++){
      int idx = tid + it*256;
      int row = idx >> 3, c8 = (idx & 7) * 8;
      *(int4*)&Ks[row][c8] =
        *(const int4*)(KV + (size_t)(b*M + cb + row)*(2*DIM) + h*HD + c8);
    }
    #pragma unroll
    for(int it=0; it<4; it++){
      int idx = tid + it*256;
      int dd = idx >> 4, c8 = (idx & 15) * 8;
      *(int4*)&Vs[dd][c8] =
        *(const int4*)(Vtg + (size_t)(bh*HD + dd)*M + cb + c8);
    }
    __syncthreads();

    s16x4 pp[8];
    #pragma unroll
    for(int cc=0; cc<8; cc++){
      f32x4 z = {};
      #pragma unroll
      for(int s=0;s<4;s++){
        s16x4 kf = *(const s16x4*)&Ks[cc*16 + l16][quad*4 + s*16];
        z = __builtin_amdgcn_mfma_f32_16x16x16bf16_1k(kf, qf[s], z, 0,0,0);
      }
      f32x4 p;
      #pragma unroll
      for(int j=0;j<4;j++) p[j] = exp2f(z[j]*sc2);
      lacc += (p[0]+p[1]) + (p[2]+p[3]);
      s16x4 pb;
      #pragma unroll
      for(int j=0;j<4;j++) pb[j] = (short)f2b(p[j]);
      pp[cc] = pb;
    }
    #pragma unroll
    for(int dn=0;dn<4;dn++){
      #pragma unroll
      for(int t=0;t<8;t++){
        s16x4 vf = *(const s16x4*)&Vs[dn*16 + l16][quad*4 + t*16];
        o[dn] = __builtin_amdgcn_mfma_f32_16x16x16bf16_1k(vf, pp[t], o[dn], 0,0,0);
      }
    }
  }

  lacc += __shfl_xor(lacc, 16, 64);
  lacc += __shfl_xor(lacc, 32, 64);
  float rl = 1.0f / lacc;

  u16* aop = AO + (size_t)(b*NQ + qt*64 + wv*16 + l16) * DIM + h*HD + quad*4;
  #pragma unroll
  for(int dn=0;dn<4;dn++){
    s16x4 ob;
    #pragma unroll
    for(int r=0;r<4;r++) ob[r] = (short)f2b(o[dn][r] * rl);
    *(s16x4*)(aop + dn*16) = ob;
  }
}

extern "C" void kernel_launch(void* const* d_in, const int* in_sizes, int n_in,
                              void* d_out, int out_size, void* d_ws, size_t ws_size,
                              hipStream_t stream){
  const float* query   = (const float*)d_in[0];
  const float* context = (const float*)d_in[1];
  const float* ln_w  = (const float*)d_in[2];
  const float* ln_b  = (const float*)d_in[3];
  const float* a1_wq = (const float*)d_in[4];
  const float* a1_wkv= (const float*)d_in[5];
  const float* a1_wp = (const float*)d_in[6];
  const float* a1_bp = (const float*)d_in[7];
  const float* m1_w1 = (const float*)d_in[8];
  const float* m1_b1 = (const float*)d_in[9];
  const float* m1_w2 = (const float*)d_in[10];
  const float* m1_b2 = (const float*)d_in[11];
  const float* a2_wq = (const float*)d_in[12];
  const float* a2_wkv= (const float*)d_in[13];
  const float* a2_wp = (const float*)d_in[14];
  const float* a2_bp = (const float*)d_in[15];
  const float* m2_w1 = (const float*)d_in[16];
  const float* m2_b1 = (const float*)d_in[17];
  const float* m2_w2 = (const float*)d_in[18];
  const float* m2_b2 = (const float*)d_in[19];
  (void)in_sizes; (void)n_in; (void)out_size; (void)ws_size;

  float* c_out = (float*)d_out;                    // output 0: c (8,1024,768) fp32
  float* q_out = c_out + (size_t)B_*NQ*IND;        // output 1: q (8,1024,768) fp32

  char* base = (char*)d_ws;
  size_t off = 0;
  auto alloc = [&](size_t elems)->u16*{
    u16* p = (u16*)(base + off);
    off += ((elems*2) + 255) & ~(size_t)255;
    return p;
  };
  u16* wq1t  = alloc((size_t)DIM*IND);
  u16* wkv1t = alloc((size_t)2*DIM*IND);
  u16* wp1t  = alloc((size_t)IND*DIM);
  u16* w11t  = alloc((size_t)HID*IND);
  u16* w21t  = alloc((size_t)IND*HID);
  u16* wq2t  = alloc((size_t)DIM*IND);
  u16* wkv2t = alloc((size_t)2*DIM*IND);
  u16* wp2t  = alloc((size_t)IND*DIM);
  u16* w12t  = alloc((size_t)HID*IND);
  u16* w22t  = alloc((size_t)IND*HID);
  u16* qn_b  = alloc((size_t)B_*NQ*IND);
  u16* cn_b  = alloc((size_t)B_*NC*IND);
  u16* Tb    = alloc((size_t)B_*NQ*IND);
  u16* Qb    = alloc((size_t)B_*NQ*DIM);
  u16* KVb   = alloc((size_t)B_*NC*2*DIM);
  u16* AOb   = alloc((size_t)B_*NQ*DIM);
  u16* Hb    = alloc((size_t)B_*NQ*HID);
  u16* Vtb   = Hb;   // alias: Hb idle during attention phases

  dim3 tb(32,8);
  wtrans_kernel<<<dim3(DIM/32,   IND/32), tb, 0, stream>>>(a1_wq,  wq1t,  IND, DIM);
  wtrans_kernel<<<dim3(2*DIM/32, IND/32), tb, 0, stream>>>(a1_wkv, wkv1t, IND, 2*DIM);
  wtrans_kernel<<<dim3(IND/32,   DIM/32), tb, 0, stream>>>(a1_wp,  wp1t,  DIM, IND);
  wtrans_kernel<<<dim3(HID/32,   IND/32), tb, 0, stream>>>(m1_w1,  w11t,  IND, HID);
  wtrans_kernel<<<dim3(IND/32,   HID/32), tb, 0, stream>>>(m1_w2,  w21t,  HID, IND);
  wtrans_kernel<<<dim3(DIM/32,   IND/32), tb, 0, stream>>>(a2_wq,  wq2t,  IND, DIM);
  wtrans_kernel<<<dim3(2*DIM/32, IND/32), tb, 0, stream>>>(a2_wkv, wkv2t, IND, 2*DIM);
  wtrans_kernel<<<dim3(IND/32,   DIM/32), tb, 0, stream>>>(a2_wp,  wp2t,  DIM, IND);
  wtrans_kernel<<<dim3(HID/32,   IND/32), tb, 0, stream>>>(m2_w1,  w12t,  IND, HID);
  wtrans_kernel<<<dim3(IND/32,   HID/32), tb, 0, stream>>>(m2_w2,  w22t,  HID, IND);

  ln_kernel<true ><<<B_*NQ, 256, 0, stream>>>(query,   ln_w, ln_b, qn_b, q_out);
  ln_kernel<false><<<B_*NC, 256, 0, stream>>>(context, ln_w, ln_b, cn_b, nullptr);

  // --- block 1: cross-attention ---
  gemm_bt<64,0,false,false><<<dim3(B_*NQ/128, DIM/64),  256, 0, stream>>>(qn_b, wq1t,  nullptr, Qb,  IND, DIM);
  gemm_bt<128,0,false,false><<<dim3(B_*NC/128, 2*DIM/128), 256, 0, stream>>>(cn_b, wkv1t, nullptr, KVb, IND, 2*DIM);
  vtrans_kernel<<<dim3(NC/64, B_*NH), 256, 0, stream>>>(KVb, Vtb, NC);
  attn_kernel<<<B_*NH*(NQ/64), 256, 0, stream>>>(Qb, KVb, Vtb, AOb, NC);
  gemm_bt<64,1,true,false><<<dim3(B_*NQ/128, IND/64), 256, 0, stream>>>(AOb, wp1t, a1_bp, c_out, DIM, IND);
  // --- MLP 1 ---
  ln_kernel<false><<<B_*NQ, 256, 0, stream>>>(c_out, ln_w, ln_b, Tb, nullptr);
  gemm_bt<128,0,true,true ><<<dim3(B_*NQ/128, HID/128), 256, 0, stream>>>(Tb, w11t, m1_b1, Hb, IND, HID);
  gemm_bt<64,2,true,false><<<dim3(B_*NQ/128, IND/64), 256, 0, stream>>>(Hb, w21t, m1_b2, c_out, HID, IND);
  // --- block 2: cross-attention (q reused, kv from LN(c)) ---
  ln_kernel<false><<<B_*NQ, 256, 0, stream>>>(c_out, ln_w, ln_b, Tb, nullptr);
  gemm_bt<64,0,false,false><<<dim3(B_*NQ/128, DIM/64),  256, 0, stream>>>(qn_b, wq2t,  nullptr, Qb,  IND, DIM);
  gemm_bt<64,0,false,false><<<dim3(B_*NQ/128, 2*DIM/64), 256, 0, stream>>>(Tb,   wkv2t, nullptr, KVb, IND, 2*DIM);
  vtrans_kernel<<<dim3(NQ/64, B_*NH), 256, 0, stream>>>(KVb, Vtb, NQ);
  attn_kernel<<<B_*NH*(NQ/64), 256, 0, stream>>>(Qb, KVb, Vtb, AOb, NQ);
  gemm_bt<64,2,true,false><<<dim3(B_*NQ/128, IND/64), 256, 0, stream>>>(AOb, wp2t, a2_bp, c_out, DIM, IND);
  // --- MLP 2 ---
  ln_kernel<false><<<B_*NQ, 256, 0, stream>>>(c_out, ln_w, ln_b, Tb, nullptr);
  gemm_bt<128,0,true,true ><<<dim3(B_*NQ/128, HID/128), 256, 0, stream>>>(Tb, w12t, m2_b1, Hb, IND, HID);
  gemm_bt<64,2,true,false><<<dim3(B_*NQ/128, IND/64), 256, 0, stream>>>(Hb, w22t, m2_b2, c_out, HID, IND);
}